// Round 14
// baseline (1415.281 us; speedup 1.0000x reference)
//
#include <hip/hip_runtime.h>
#include <hip/hip_bf16.h>

#define VOCAB 4096
#define BB 4
#define LL 2048
#define SEG 16
#define SEGL 128  // LL/SEG

typedef __hip_bfloat16 bf16;
typedef __bf16 bf16x8 __attribute__((ext_vector_type(8)));
typedef float f32x4 __attribute__((ext_vector_type(4)));

__device__ __forceinline__ void gload16(const void* g, void* l) {
  __builtin_amdgcn_global_load_lds(
      (const __attribute__((address_space(1))) unsigned int*)g,
      (__attribute__((address_space(3))) unsigned int*)l, 16, 0, 0);
}

__device__ __forceinline__ bf16x8 as_bf(f32x4 v) {
  union { f32x4 f; bf16x8 b; } u;
  u.f = v;
  return u.b;
}

// ---------------- transpose f32 [K][N] -> bf16 [N][K] ----------------
__global__ void transpose_f32_bf16(const float* __restrict__ in,
                                   bf16* __restrict__ out, int K, int N) {
  __shared__ float tile[32][33];
  int bx = blockIdx.x;  // tile along N
  int by = blockIdx.y;  // tile along K
  int x = bx * 32 + threadIdx.x;
#pragma unroll
  for (int i = threadIdx.y; i < 32; i += 8)
    tile[i][threadIdx.x] = in[(size_t)(by * 32 + i) * N + x];
  __syncthreads();
  int k = by * 32 + threadIdx.x;
#pragma unroll
  for (int i = threadIdx.y; i < 32; i += 8)
    out[(size_t)(bx * 32 + i) * K + k] = __float2bfloat16(tile[threadIdx.x][i]);
}

// -------- ctx pass A: per-segment sigmoid column sums --------
__global__ void ctx_partial(const int* __restrict__ idx,
                            const float* __restrict__ Mlog,
                            float* __restrict__ segsum) {
  int b = blockIdx.x / (16 * SEG);
  int rem = blockIdx.x % (16 * SEG);
  int chunk = rem / SEG;
  int s = rem % SEG;
  int col = chunk * 256 + threadIdx.x;
  __shared__ int sidx[SEGL];
  if (threadIdx.x < SEGL)
    sidx[threadIdx.x] = idx[b * LL + s * SEGL + threadIdx.x];
  __syncthreads();
  const float* base = Mlog + col;
  float a0 = 0.f, a1 = 0.f, a2 = 0.f, a3 = 0.f;
#pragma unroll 4
  for (int t = 0; t < SEGL; t += 4) {
    float v0 = base[(size_t)sidx[t + 0] * VOCAB];
    float v1 = base[(size_t)sidx[t + 1] * VOCAB];
    float v2 = base[(size_t)sidx[t + 2] * VOCAB];
    float v3 = base[(size_t)sidx[t + 3] * VOCAB];
    a0 += 1.f / (1.f + __expf(-v0));
    a1 += 1.f / (1.f + __expf(-v1));
    a2 += 1.f / (1.f + __expf(-v2));
    a3 += 1.f / (1.f + __expf(-v3));
  }
  segsum[(size_t)blockIdx.x * 256 + threadIdx.x] = (a0 + a1) + (a2 + a3);
}

// -------- ctx pass B: replay segment with offset, write running mean --------
__global__ void ctx_final(const int* __restrict__ idx,
                          const float* __restrict__ Mlog,
                          const float* __restrict__ segsum,
                          bf16* __restrict__ ctx) {
  int b = blockIdx.x / (16 * SEG);
  int rem = blockIdx.x % (16 * SEG);
  int chunk = rem / SEG;
  int s = rem % SEG;
  int col = chunk * 256 + threadIdx.x;
  __shared__ int sidx[SEGL];
  if (threadIdx.x < SEGL)
    sidx[threadIdx.x] = idx[b * LL + s * SEGL + threadIdx.x];
  __syncthreads();
  const float* ss = segsum + (size_t)((b * 16 + chunk) * SEG) * 256 + threadIdx.x;
  float acc = 0.f;
  for (int s2 = 0; s2 < s; ++s2) acc += ss[(size_t)s2 * 256];
  const float* base = Mlog + col;
  bf16* outp = ctx + ((size_t)b * LL + (size_t)s * SEGL) * VOCAB + col;
#pragma unroll 8
  for (int t = 0; t < SEGL; ++t) {
    float v = base[(size_t)sidx[t] * VOCAB];
    acc += 1.f / (1.f + __expf(-v));
    float inv = __fdividef(1.f, (float)(s * SEGL + t + 1));
    outp[(size_t)t * VOCAB] = __float2bfloat16(acc * inv);
  }
}

// ---- 128x256 bf16 GEMM, BK=32, 2 blocks/CU (block-level TLP) ----
// r13 post-mortem: intra-block scheduling is exhausted (r2/r3/r7/r8/r13 all
// ~4464 cyc/tile; barriers lockstep the block's waves -> LDS + MFMA ADD).
// This kernel: 256 thr (4 waves), tile 128x256, BK=32, LDS 24KB/buf dbuf
// 48KB -> TWO independent blocks/CU. One block's read/lgkm phase overlaps
// the other's MFMA with no shared barriers (m97's implicit-overlap
// mechanism). Wave = 128x64 out (acc 8x4 f32x4 = 128 AGPR); 2 waves/SIMD
// -> 256-reg unified budget: acc 128 + ~90 arch, no spill.
// Per tile per wave: 12 ds_read_b128 (A 8m, B 4n; one read per fragment
// since BK=32 = MFMA K), 32 MFMA. Chunk-XOR LDS: slot(row,kc) at byte
// row*64 + ((kc^(row&3))<<4); reads hit 8 bank-groups x 2 lanes = free.
// Sync = r9-PROVEN conservative discipline, one phase/tile:
//   STG_TILE(t+1 -> ~p)  (6 gloads, issued first: DMA covered by
//   12 ds_reads of p      reads+MFMA ~1200-1800 cyc >= 900 HBM)
//   LGKM0 + SB0; 32 MFMA; VMW(0); BAR
// Hazards: RAW stage->read via VMW(0)+BAR at end of staging tile; WAR via
// LGKM0-before-BAR. No partial vmcnt, no cross-tile register carrying.
// EPI==0: out = bf16 gelu_exact(C)   EPI==1: out = f32 C

#define BAR() asm volatile("s_barrier" ::: "memory")
#define LGKM0() asm volatile("s_waitcnt lgkmcnt(0)" ::: "memory")
#define VMW(n_) asm volatile("s_waitcnt vmcnt(" #n_ ")" ::: "memory")
#define SB0() __builtin_amdgcn_sched_barrier(0)
#define P1() __builtin_amdgcn_s_setprio(1)
#define P0() __builtin_amdgcn_s_setprio(0)

// stage tile T_ (A 128x32 + B 256x32) into buffer b_ ; 6 gload16/thread
#define STG_TILE(T_, b_)                                      \
  {                                                           \
    const size_t ko_ = (size_t)(T_)*32;                       \
    bf16* dA_ = sm + (b_)*12288 + tid * 8;                    \
    gload16(AsrcS + ko_, dA_);                                \
    gload16(AsrcS + 64 * (size_t)K + ko_, dA_ + 2048);        \
    bf16* dB_ = sm + (b_)*12288 + 4096 + tid * 8;             \
    gload16(BsrcS + ko_, dB_);                                \
    gload16(BsrcS + 64 * (size_t)K + ko_, dB_ + 2048);        \
    gload16(BsrcS + 128 * (size_t)K + ko_, dB_ + 4096);       \
    gload16(BsrcS + 192 * (size_t)K + ko_, dB_ + 6144);       \
  }

// one asm LDS read: 16B into a f32x4, literal byte offset
#define RD1(dst_, base_, off_)                       \
  asm volatile("ds_read_b128 %0, %1 offset:%2"       \
               : "=v"(dst_)                          \
               : "v"(base_), "i"(off_)               \
               : "memory")

// all 12 fragment reads for one tile from buffer bases aB_/bB_
#define RD_ALL(aB_, bB_)        \
  RD1(Ac[0], aB_, 0);           \
  RD1(Ac[1], aB_, 1024);        \
  RD1(Ac[2], aB_, 2048);        \
  RD1(Ac[3], aB_, 3072);        \
  RD1(Ac[4], aB_, 4096);        \
  RD1(Ac[5], aB_, 5120);        \
  RD1(Ac[6], aB_, 6144);        \
  RD1(Ac[7], aB_, 7168);        \
  RD1(Bc[0], bB_, 0);           \
  RD1(Bc[1], bB_, 1024);        \
  RD1(Bc[2], bB_, 2048);        \
  RD1(Bc[3], bB_, 3072);

#define MQ_ALL()                                                       \
  _Pragma("unroll") for (int i_ = 0; i_ < 8; ++i_)                     \
      _Pragma("unroll") for (int j_ = 0; j_ < 4; ++j_) {               \
    acc[i_][j_] = __builtin_amdgcn_mfma_f32_16x16x32_bf16(             \
        as_bf(Ac[i_]), as_bf(Bc[j_]), acc[i_][j_], 0, 0, 0);           \
  }

// one K-tile, conservative one-phase discipline
#define TILE_BODY(T_, p_, aB_, bB_)                  \
  {                                                  \
    if ((T_) + 1 < NT) STG_TILE((T_) + 1, (p_) ^ 1); \
    RD_ALL(aB_, bB_);                                \
    LGKM0();                                         \
    SB0();                                           \
    P1();                                            \
    MQ_ALL();                                        \
    P0();                                            \
    VMW(0);                                          \
    BAR();                                           \
  }

template <int EPI>
__global__ __launch_bounds__(256, 2) void gemm128(const bf16* __restrict__ A,
                                                  const bf16* __restrict__ Bt,
                                                  const float* __restrict__ bias,
                                                  void* __restrict__ outv,
                                                  int M, int N, int K) {
  __shared__ __align__(16) bf16 sm[24576];  // 48 KiB: 2 x (A 8KB | B 16KB)
  const int tid = threadIdx.x;
  const int wave = tid >> 6;
  const int lane = tid & 63;
  const int nwg = gridDim.x;
  const int bid = blockIdx.x;
  const int swz = (bid & 7) * (nwg >> 3) + (bid >> 3);  // nwg % 8 == 0
  const int gn = N >> 8;                                // tiles along N (256)
  const int bm0 = (swz / gn) << 7;                      // 128-row tile
  const int bn0 = (swz % gn) << 8;                      // 256-col tile
  const int wn = wave << 6;                             // wave's 64 cols
  const int rsel = lane & 15;
  const int ksel = lane >> 4;

  // staging source: chunk q = tid + s*256 -> row = (tid>>2)+64s,
  // kc = (tid&3)^((tid>>2)&3)  (row&3 invariant mod 64)
  const int r0 = tid >> 2;
  const int kcA = (tid & 3) ^ (r0 & 3);
  const bf16* AsrcS = A + (size_t)(bm0 + r0) * K + kcA * 8;
  const bf16* BsrcS = Bt + (size_t)(bn0 + r0) * K + kcA * 8;
  const int NT = K >> 5;

  // 32-bit LDS byte bases for asm ds_read (chunk-XOR folded in):
  // A frag i: byte = (i*16+rsel)*64 + ((ksel^(rsel&3))<<4)   (i -> i*1024)
  // B frag j: byte = 8192 + (wn+j*16+rsel)*64 + ((ksel^(rsel&3))<<4)
  const unsigned smbase =
      (unsigned)(unsigned long long)(__attribute__((address_space(3)))
                                     bf16*)sm;
  const unsigned xk = (unsigned)((ksel ^ (rsel & 3)) << 4);
  const unsigned aB0 = smbase + (unsigned)(rsel * 64) + xk;
  const unsigned bB0 = smbase + 8192u + (unsigned)((wn + rsel) * 64) + xk;
  const unsigned aB1 = aB0 + 24576u;
  const unsigned bB1 = bB0 + 24576u;

  f32x4 acc[8][4];
#pragma unroll
  for (int i = 0; i < 8; ++i)
#pragma unroll
    for (int j = 0; j < 4; ++j) acc[i][j] = (f32x4){0.f, 0.f, 0.f, 0.f};

  f32x4 Ac[8], Bc[4];

  // prologue: stage tile0 -> buf0, full drain + barrier
  STG_TILE(0, 0);
  VMW(0);
  BAR();

  for (int t = 0; t < NT; t += 2) {
    TILE_BODY(t, 0, aB0, bB0);
    TILE_BODY(t + 1, 1, aB1, bB1);
  }

  // epilogue; C/D layout: col = lane&15, row = (lane>>4)*4 + reg
  const int cl = lane & 15;
  const int rg = lane >> 4;
#pragma unroll
  for (int i = 0; i < 8; ++i) {
    int grow = bm0 + i * 16 + rg * 4;
#pragma unroll
    for (int j = 0; j < 4; ++j) {
      int col = bn0 + wn + j * 16 + cl;
      float bv = bias[col];
#pragma unroll
      for (int r = 0; r < 4; ++r) {
        size_t o = (size_t)(grow + r) * N + col;
        float v = acc[i][j][r] + bv;
        if (EPI == 0) {
          float g = 0.5f * v * (1.f + erff(v * 0.70710678118654752f));
          ((bf16*)outv)[o] = __float2bfloat16(g);
        } else {
          ((float*)outv)[o] = v;
        }
      }
    }
  }
}

extern "C" void kernel_launch(void* const* d_in, const int* in_sizes, int n_in,
                              void* d_out, int out_size, void* d_ws,
                              size_t ws_size, hipStream_t stream) {
  const int* idx = (const int*)d_in[0];       // [B,L]
  const float* Mlog = (const float*)d_in[1];  // [V,V]
  const float* W1 = (const float*)d_in[2];    // [V,2V]
  const float* b1 = (const float*)d_in[3];    // [2V]
  const float* W2 = (const float*)d_in[4];    // [2V,V]
  const float* b2 = (const float*)d_in[5];    // [V]
  float* out = (float*)d_out;                 // [B,L,V] f32

  char* ws = (char*)d_ws;
  const size_t MB64 = 64ull << 20;
  bf16* ctx = (bf16*)ws;             // 64 MiB  [8192][4096] (dead after GEMM1)
  bf16* W2t = (bf16*)ws;             // aliases ctx: [4096][8192]
  bf16* W1t = (bf16*)(ws + MB64);    // 64 MiB  [8192][4096]
  bf16* h = (bf16*)(ws + 2 * MB64);  // 128 MiB [8192][8192]
  float* segsum = (float*)h;         // 1 MiB, dead before GEMM1 writes h
  (void)ws_size;

  dim3 tb(32, 8);
  // W1^T cast
  transpose_f32_bf16<<<dim3(8192 / 32, 4096 / 32), tb, 0, stream>>>(W1, W1t,
                                                                    4096, 8192);
  // ctx = causal-mean(sigmoid(M)[idx]), segment-parallel two-pass
  ctx_partial<<<BB * 16 * SEG, 256, 0, stream>>>(idx, Mlog, segsum);
  ctx_final<<<BB * 16 * SEG, 256, 0, stream>>>(idx, Mlog, segsum, ctx);
  // h = gelu(ctx @ W1 + b1)  -> bf16   (grid 64x32 = 2048 blocks)
  gemm128<0><<<(8192 / 128) * (8192 / 256), 256, 0, stream>>>(
      ctx, W1t, b1, h, 8192, 8192, 4096);
  // W2^T cast (reuses ctx space)
  transpose_f32_bf16<<<dim3(4096 / 32, 8192 / 32), tb, 0, stream>>>(W2, W2t,
                                                                    8192, 4096);
  // out = h @ W2 + b2  -> f32   (grid 64x16 = 1024 blocks)
  gemm128<1><<<(8192 / 128) * (4096 / 256), 256, 0, stream>>>(
      h, W2t, b2, out, 8192, 4096, 8192);
}

// Round 15
// 1088.372 us; speedup vs baseline: 1.3004x; 1.3004x over previous
//
#include <hip/hip_runtime.h>
#include <hip/hip_bf16.h>

#define VOCAB 4096
#define BB 4
#define LL 2048
#define SEG 16
#define SEGL 128  // LL/SEG

typedef __hip_bfloat16 bf16;
typedef __bf16 bf16x8 __attribute__((ext_vector_type(8)));
typedef float f32x4 __attribute__((ext_vector_type(4)));

__device__ __forceinline__ void gload16(const void* g, void* l) {
  __builtin_amdgcn_global_load_lds(
      (const __attribute__((address_space(1))) unsigned int*)g,
      (__attribute__((address_space(3))) unsigned int*)l, 16, 0, 0);
}

__device__ __forceinline__ bf16x8 as_bf(f32x4 v) {
  union { f32x4 f; bf16x8 b; } u;
  u.f = v;
  return u.b;
}

// ---------------- transpose f32 [K][N] -> bf16 [N][K] ----------------
__global__ void transpose_f32_bf16(const float* __restrict__ in,
                                   bf16* __restrict__ out, int K, int N) {
  __shared__ float tile[32][33];
  int bx = blockIdx.x;  // tile along N
  int by = blockIdx.y;  // tile along K
  int x = bx * 32 + threadIdx.x;
#pragma unroll
  for (int i = threadIdx.y; i < 32; i += 8)
    tile[i][threadIdx.x] = in[(size_t)(by * 32 + i) * N + x];
  __syncthreads();
  int k = by * 32 + threadIdx.x;
#pragma unroll
  for (int i = threadIdx.y; i < 32; i += 8)
    out[(size_t)(bx * 32 + i) * K + k] = __float2bfloat16(tile[threadIdx.x][i]);
}

// -------- ctx pass A: per-segment sigmoid column sums --------
__global__ void ctx_partial(const int* __restrict__ idx,
                            const float* __restrict__ Mlog,
                            float* __restrict__ segsum) {
  int b = blockIdx.x / (16 * SEG);
  int rem = blockIdx.x % (16 * SEG);
  int chunk = rem / SEG;
  int s = rem % SEG;
  int col = chunk * 256 + threadIdx.x;
  __shared__ int sidx[SEGL];
  if (threadIdx.x < SEGL)
    sidx[threadIdx.x] = idx[b * LL + s * SEGL + threadIdx.x];
  __syncthreads();
  const float* base = Mlog + col;
  float a0 = 0.f, a1 = 0.f, a2 = 0.f, a3 = 0.f;
#pragma unroll 4
  for (int t = 0; t < SEGL; t += 4) {
    float v0 = base[(size_t)sidx[t + 0] * VOCAB];
    float v1 = base[(size_t)sidx[t + 1] * VOCAB];
    float v2 = base[(size_t)sidx[t + 2] * VOCAB];
    float v3 = base[(size_t)sidx[t + 3] * VOCAB];
    a0 += 1.f / (1.f + __expf(-v0));
    a1 += 1.f / (1.f + __expf(-v1));
    a2 += 1.f / (1.f + __expf(-v2));
    a3 += 1.f / (1.f + __expf(-v3));
  }
  segsum[(size_t)blockIdx.x * 256 + threadIdx.x] = (a0 + a1) + (a2 + a3);
}

// -------- ctx pass B: replay segment with offset, write running mean --------
__global__ void ctx_final(const int* __restrict__ idx,
                          const float* __restrict__ Mlog,
                          const float* __restrict__ segsum,
                          bf16* __restrict__ ctx) {
  int b = blockIdx.x / (16 * SEG);
  int rem = blockIdx.x % (16 * SEG);
  int chunk = rem / SEG;
  int s = rem % SEG;
  int col = chunk * 256 + threadIdx.x;
  __shared__ int sidx[SEGL];
  if (threadIdx.x < SEGL)
    sidx[threadIdx.x] = idx[b * LL + s * SEGL + threadIdx.x];
  __syncthreads();
  const float* ss = segsum + (size_t)((b * 16 + chunk) * SEG) * 256 + threadIdx.x;
  float acc = 0.f;
  for (int s2 = 0; s2 < s; ++s2) acc += ss[(size_t)s2 * 256];
  const float* base = Mlog + col;
  bf16* outp = ctx + ((size_t)b * LL + (size_t)s * SEGL) * VOCAB + col;
#pragma unroll 8
  for (int t = 0; t < SEGL; ++t) {
    float v = base[(size_t)sidx[t] * VOCAB];
    acc += 1.f / (1.f + __expf(-v));
    float inv = __fdividef(1.f, (float)(s * SEGL + t + 1));
    outp[(size_t)t * VOCAB] = __float2bfloat16(acc * inv);
  }
}

// ---- 256x256 bf16 GEMM — r13 (balanced+carry+counted vmcnt) + m201-style
// per-phase double barriers. Each phase: {issue ds_reads ; issue stage ;
// BAR (reads in flight under barrier-wait) ; LGKM0+SB0 ; setprio 16 MFMA ;
// BAR}. Wait counts/positions byte-identical to r13 (proven): top VMW(4)
// steady / VMW(0) last tile (drains A(t)); mid VMW(6) (publishes B(t+1,h0)
// for ph4's carry-read from ~p). Stages: ph1/ph2 A(t+1)->~p, ph3/ph4
// B(t+2)->p. B0 carried in regs across the tile boundary (bX/bY rotation).
// Adding barriers strictly strengthens r13's race-free ledger.
// EPI==0: out = bf16 gelu_exact(C)   EPI==1: out = f32 C

#define BAR() asm volatile("s_barrier" ::: "memory")
#define LGKM0() asm volatile("s_waitcnt lgkmcnt(0)" ::: "memory")
#define VMW(n_) asm volatile("s_waitcnt vmcnt(" #n_ ")" ::: "memory")
#define SB0() __builtin_amdgcn_sched_barrier(0)
#define P1() __builtin_amdgcn_s_setprio(1)
#define P0() __builtin_amdgcn_s_setprio(0)

#define STG_A(t_, h_, b_)                                           \
  {                                                                 \
    const bf16* s_ = Asrc + (size_t)(h_)*128 * K + (size_t)(t_)*64; \
    bf16* d_ = sm + (b_)*32768 + (h_)*8192 + wave * 512;            \
    gload16(s_, d_);                                                \
    gload16(s_ + rowK64, d_ + 4096);                                \
  }
#define STG_B(t_, h_, b_)                                           \
  {                                                                 \
    const bf16* s_ = Bsrc + (size_t)(h_)*128 * K + (size_t)(t_)*64; \
    bf16* d_ = sm + (b_)*32768 + 16384 + (h_)*8192 + wave * 512;    \
    gload16(s_, d_);                                                \
    gload16(s_ + rowK64, d_ + 4096);                                \
  }

// one asm LDS read: 16B into a f32x4, literal byte offset
#define RD1(dst_, base_, off_)                       \
  asm volatile("ds_read_b128 %0, %1 offset:%2"       \
               : "=v"(dst_)                          \
               : "v"(base_), "i"(off_)               \
               : "memory")

// A quadrant mh_: 8 reads (4 m-frags x 2 k-chunks) -> af
#define RD_A(b0_, b1_, mh_)                    \
  RD1(af[0][0], b0_, (mh_)*16384 + 0);         \
  RD1(af[0][1], b1_, (mh_)*16384 + 0);         \
  RD1(af[1][0], b0_, (mh_)*16384 + 2048);      \
  RD1(af[1][1], b1_, (mh_)*16384 + 2048);      \
  RD1(af[2][0], b0_, (mh_)*16384 + 4096);      \
  RD1(af[2][1], b1_, (mh_)*16384 + 4096);      \
  RD1(af[3][0], b0_, (mh_)*16384 + 6144);      \
  RD1(af[3][1], b1_, (mh_)*16384 + 6144);

// B quadrant nh_ into dst_: 4 reads
#define RD_B(dst_, b0_, b1_, nh_)              \
  RD1(dst_[0][0], b0_, (nh_)*16384 + 0);       \
  RD1(dst_[0][1], b1_, (nh_)*16384 + 0);       \
  RD1(dst_[1][0], b0_, (nh_)*16384 + 2048);    \
  RD1(dst_[1][1], b1_, (nh_)*16384 + 2048);

#define MQ(mh_, nh_, B_)                                                     \
  _Pragma("unroll") for (int i_ = 0; i_ < 4; ++i_)                           \
      _Pragma("unroll") for (int j_ = 0; j_ < 2; ++j_) {                     \
    f32x4& c_ = acc[(mh_)*4 + i_][(nh_)*2 + j_];                             \
    c_ = __builtin_amdgcn_mfma_f32_16x16x32_bf16(as_bf(af[i_][0]),           \
                                                 as_bf(B_[j_][0]), c_, 0, 0, \
                                                 0);                         \
    c_ = __builtin_amdgcn_mfma_f32_16x16x32_bf16(as_bf(af[i_][1]),           \
                                                 as_bf(B_[j_][1]), c_, 0, 0, \
                                                 0);                         \
  }

// One K-tile. p_: buffer (literal 0/1). aK/bK: ds-read bases of buf p.
// bn0_/bn1_: B bases of buf ~p (carry-read). Bc_: carried B0(t).
// Bn_: slot for B1(t), then refilled with B0(t+1).
#define TILE_BODY(T_, p_, aK0_, aK1_, bK0_, bK1_, bn0_, bn1_, Bc_, Bn_) \
  {                                                                     \
    if ((T_) + 1 < NT) { VMW(4); } else { VMW(0); }                     \
    BAR();                                                              \
    /* ph1: rd A0 ; stg A(t+1,h0)->~p ; MFMA (0,0)=A0 x Bc */           \
    RD_A(aK0_, aK1_, 0);                                                \
    if ((T_) + 1 < NT) STG_A((T_) + 1, 0, (p_) ^ 1);                    \
    BAR();                                                              \
    LGKM0();                                                            \
    SB0();                                                              \
    P1(); MQ(0, 0, Bc_); P0();                                          \
    BAR();                                                              \
    /* ph2: rd B1->Bn ; stg A(t+1,h1)->~p ; MFMA (0,1)=A0 x Bn */       \
    RD_B(Bn_, bK0_, bK1_, 1);                                           \
    if ((T_) + 1 < NT) STG_A((T_) + 1, 1, (p_) ^ 1);                    \
    BAR();                                                              \
    LGKM0();                                                            \
    SB0();                                                              \
    P1(); MQ(0, 1, Bn_); P0();                                          \
    BAR();                                                              \
    /* mid: publish B(t+1,h0) (staged (t-1).ph3) */                     \
    VMW(6);                                                             \
    BAR();                                                              \
    /* ph3: rd A1 ; stg B(t+2,h0)->p ; MFMA (1,1)=A1 x Bn */            \
    RD_A(aK0_, aK1_, 1);                                                \
    if ((T_) + 2 < NT) STG_B((T_) + 2, 0, (p_));                        \
    BAR();                                                              \
    LGKM0();                                                            \
    SB0();                                                              \
    P1(); MQ(1, 1, Bn_); P0();                                          \
    BAR();                                                              \
    /* ph4: rd B0(t+1) from ~p -> Bn ; stg B(t+2,h1)->p ; (1,0) */      \
    if ((T_) + 1 < NT) RD_B(Bn_, bn0_, bn1_, 0);                        \
    if ((T_) + 2 < NT) STG_B((T_) + 2, 1, (p_));                        \
    BAR();                                                              \
    LGKM0();                                                            \
    SB0();                                                              \
    P1(); MQ(1, 0, Bc_); P0();                                          \
  }

template <int EPI>
__global__ __launch_bounds__(512) void gemm256(const bf16* __restrict__ A,
                                               const bf16* __restrict__ Bt,
                                               const float* __restrict__ bias,
                                               void* __restrict__ outv, int M,
                                               int N, int K) {
  __shared__ __align__(16) bf16 sm[65536];  // 128 KiB: 2 x (A 32KB | B 32KB)
  const int tid = threadIdx.x;
  const int wave = tid >> 6;
  const int lane = tid & 63;
  const int nwg = gridDim.x;
  const int bid = blockIdx.x;
  const int swz = (bid & 7) * (nwg >> 3) + (bid >> 3);  // nwg % 8 == 0
  const int gn = N >> 8;
  const int bm0 = (swz / gn) << 8;
  const int bn0 = (swz % gn) << 8;
  const int wm64 = (wave >> 2) << 6;  // wave m-offset within half: 0 or 64
  const int wn32 = (wave & 3) << 5;   // wave n-offset within half: 0..96
  const int rsel = lane & 15;
  const int ksel = lane >> 4;
  const int xorv = rsel & 7;

  // staging source: thread covers slots tid and tid+512 of each half-tile;
  // slot p -> row=p>>3, kc=(p&7)^(row&7)
  const int r0 = tid >> 3;
  const int kc0 = (tid & 7) ^ (r0 & 7);
  const bf16* Asrc = A + (size_t)(bm0 + r0) * K + kc0 * 8;
  const bf16* Bsrc = Bt + (size_t)(bn0 + r0) * K + kc0 * 8;
  const size_t rowK64 = (size_t)64 * K;
  const int NT = K >> 6;

  // 32-bit LDS byte bases for asm ds_read (chunk-XOR folded in)
  const unsigned smbase =
      (unsigned)(unsigned long long)(__attribute__((address_space(3)))
                                     bf16*)sm;
  const unsigned kT0 = (unsigned)((ksel ^ xorv) << 4);
  const unsigned kT1 = (unsigned)(((ksel + 4) ^ xorv) << 4);
  const unsigned aRow = (unsigned)((wm64 + rsel) * 128);
  const unsigned bRow = (unsigned)((wn32 + rsel) * 128);
  const unsigned a00 = smbase + aRow + kT0;
  const unsigned a10 = smbase + aRow + kT1;
  const unsigned b00 = smbase + 32768u + bRow + kT0;
  const unsigned b10 = smbase + 32768u + bRow + kT1;
  const unsigned a01 = a00 + 65536u, a11 = a10 + 65536u;
  const unsigned b01 = b00 + 65536u, b11 = b10 + 65536u;

  f32x4 acc[8][4];
#pragma unroll
  for (int i = 0; i < 8; ++i)
#pragma unroll
    for (int j = 0; j < 4; ++j) acc[i][j] = (f32x4){0.f, 0.f, 0.f, 0.f};

  f32x4 af[4][2], bX[2][2], bY[2][2];

  // prologue: A(0)->buf0, B(0)->buf0, B(1)->buf1 (12 gloads, FIFO order);
  // VMW(4) drains A(0)+B(0) (first 8), leaves B(1) in flight; then read the
  // initial carried B0(0) into bX (drained by t0.ph1's LGKM0).
  STG_A(0, 0, 0);
  STG_A(0, 1, 0);
  STG_B(0, 0, 0);
  STG_B(0, 1, 0);
  STG_B(1, 0, 1);
  STG_B(1, 1, 1);
  VMW(4);
  BAR();
  RD_B(bX, b00, b10, 0);

  for (int t = 0; t < NT; t += 2) {
    TILE_BODY(t, 0, a00, a10, b00, b10, b01, b11, bX, bY);
    TILE_BODY(t + 1, 1, a01, a11, b01, b11, b00, b10, bY, bX);
  }

  // epilogue; C/D layout: col = lane&15, row = (lane>>4)*4 + reg
  const int cl = lane & 15;
  const int rg = lane >> 4;
#pragma unroll
  for (int m = 0; m < 8; ++m) {
    int grow = bm0 + ((m >> 2) << 7) + wm64 + ((m & 3) << 4) + rg * 4;
#pragma unroll
    for (int n = 0; n < 4; ++n) {
      int col = bn0 + ((n >> 1) << 7) + wn32 + ((n & 1) << 4) + cl;
      float bv = bias[col];
#pragma unroll
      for (int r = 0; r < 4; ++r) {
        size_t o = (size_t)(grow + r) * N + col;
        float v = acc[m][n][r] + bv;
        if (EPI == 0) {
          float g = 0.5f * v * (1.f + erff(v * 0.70710678118654752f));
          ((bf16*)outv)[o] = __float2bfloat16(g);
        } else {
          ((float*)outv)[o] = v;
        }
      }
    }
  }
}

extern "C" void kernel_launch(void* const* d_in, const int* in_sizes, int n_in,
                              void* d_out, int out_size, void* d_ws,
                              size_t ws_size, hipStream_t stream) {
  const int* idx = (const int*)d_in[0];       // [B,L]
  const float* Mlog = (const float*)d_in[1];  // [V,V]
  const float* W1 = (const float*)d_in[2];    // [V,2V]
  const float* b1 = (const float*)d_in[3];    // [2V]
  const float* W2 = (const float*)d_in[4];    // [2V,V]
  const float* b2 = (const float*)d_in[5];    // [V]
  float* out = (float*)d_out;                 // [B,L,V] f32

  char* ws = (char*)d_ws;
  const size_t MB64 = 64ull << 20;
  bf16* ctx = (bf16*)ws;             // 64 MiB  [8192][4096] (dead after GEMM1)
  bf16* W2t = (bf16*)ws;             // aliases ctx: [4096][8192]
  bf16* W1t = (bf16*)(ws + MB64);    // 64 MiB  [8192][4096]
  bf16* h = (bf16*)(ws + 2 * MB64);  // 128 MiB [8192][8192]
  float* segsum = (float*)h;         // 1 MiB, dead before GEMM1 writes h
  (void)ws_size;

  dim3 tb(32, 8);
  // W1^T cast
  transpose_f32_bf16<<<dim3(8192 / 32, 4096 / 32), tb, 0, stream>>>(W1, W1t,
                                                                    4096, 8192);
  // ctx = causal-mean(sigmoid(M)[idx]), segment-parallel two-pass
  ctx_partial<<<BB * 16 * SEG, 256, 0, stream>>>(idx, Mlog, segsum);
  ctx_final<<<BB * 16 * SEG, 256, 0, stream>>>(idx, Mlog, segsum, ctx);
  // h = gelu(ctx @ W1 + b1)  -> bf16
  gemm256<0><<<(8192 / 256) * (8192 / 256), 512, 0, stream>>>(
      ctx, W1t, b1, h, 8192, 8192, 4096);
  // W2^T cast (reuses ctx space)
  transpose_f32_bf16<<<dim3(4096 / 32, 8192 / 32), tb, 0, stream>>>(W2, W2t,
                                                                    8192, 4096);
  // out = h @ W2 + b2  -> f32
  gemm256<1><<<(8192 / 256) * (4096 / 256), 512, 0, stream>>>(
      h, W2t, b2, out, 8192, 4096, 8192);
}

// Round 16
// 823.485 us; speedup vs baseline: 1.7186x; 1.3217x over previous
//
#include <hip/hip_runtime.h>
#include <hip/hip_bf16.h>

#define VOCAB 4096
#define BB 4
#define LL 2048
#define SEG 16
#define SEGL 128  // LL/SEG
#define CH 16     // column chunks of 512 over N=8192

typedef __hip_bfloat16 bf16;
typedef __bf16 bf16x8 __attribute__((ext_vector_type(8)));
typedef float f32x4 __attribute__((ext_vector_type(4)));

__device__ __forceinline__ void gload16(const void* g, void* l) {
  __builtin_amdgcn_global_load_lds(
      (const __attribute__((address_space(1))) unsigned int*)g,
      (__attribute__((address_space(3))) unsigned int*)l, 16, 0, 0);
}

__device__ __forceinline__ bf16x8 as_bf(f32x4 v) {
  union { f32x4 f; bf16x8 b; } u;
  u.f = v;
  return u.b;
}

// ---------------- transpose f32 [K][N] -> bf16 [N][K] ----------------
__global__ void transpose_f32_bf16(const float* __restrict__ in,
                                   bf16* __restrict__ out, int K, int N) {
  __shared__ float tile[32][33];
  int bx = blockIdx.x;  // tile along N
  int by = blockIdx.y;  // tile along K
  int x = bx * 32 + threadIdx.x;
#pragma unroll
  for (int i = threadIdx.y; i < 32; i += 8)
    tile[i][threadIdx.x] = in[(size_t)(by * 32 + i) * N + x];
  __syncthreads();
  int k = by * 32 + threadIdx.x;
#pragma unroll
  for (int i = threadIdx.y; i < 32; i += 8)
    out[(size_t)(bx * 32 + i) * K + k] = __float2bfloat16(tile[threadIdx.x][i]);
}

// ---------------- R = sigmoid(Mlog), f32 -> bf16, 4 elems/thread ----------
__global__ void sigmoid_bf16(const float* __restrict__ in,
                             bf16* __restrict__ out) {
  size_t i = ((size_t)blockIdx.x * 256 + threadIdx.x) * 4;
  float4 v = *(const float4*)(in + i);
  bf16 tmp[4];
  tmp[0] = __float2bfloat16(1.f / (1.f + __expf(-v.x)));
  tmp[1] = __float2bfloat16(1.f / (1.f + __expf(-v.y)));
  tmp[2] = __float2bfloat16(1.f / (1.f + __expf(-v.z)));
  tmp[3] = __float2bfloat16(1.f / (1.f + __expf(-v.w)));
  *(ushort4*)(out + i) = *(ushort4*)tmp;
}

// -------- pass A: per-segment column sums of P[idx] --------
// grid: B * CH * SEG blocks, 256 thr, 2 cols/thread (bf16x2 loads)
__global__ void psumA(const int* __restrict__ idx, const bf16* __restrict__ P,
                      float* __restrict__ segsum) {
  int b = blockIdx.x / (CH * SEG);
  int rem = blockIdx.x % (CH * SEG);
  int chunk = rem / SEG;
  int s = rem % SEG;
  int col = chunk * 512 + threadIdx.x * 2;
  __shared__ int sidx[SEGL];
  if (threadIdx.x < SEGL)
    sidx[threadIdx.x] = idx[b * LL + s * SEGL + threadIdx.x];
  __syncthreads();
  const __hip_bfloat162* base = (const __hip_bfloat162*)P + (col >> 1);
  float a0 = 0.f, a1 = 0.f;
#pragma unroll 8
  for (int t = 0; t < SEGL; ++t) {
    __hip_bfloat162 v = base[(size_t)sidx[t] * 4096];
    a0 += __bfloat162float(v.x);
    a1 += __bfloat162float(v.y);
  }
  *((float2*)(segsum + (size_t)blockIdx.x * 512) + threadIdx.x) =
      make_float2(a0, a1);
}

// -------- pass B: prefix + running mean + bias + exact gelu -> h bf16 -----
__global__ void psumB(const int* __restrict__ idx, const bf16* __restrict__ P,
                      const float* __restrict__ segsum,
                      const float* __restrict__ b1, bf16* __restrict__ h) {
  int b = blockIdx.x / (CH * SEG);
  int rem = blockIdx.x % (CH * SEG);
  int chunk = rem / SEG;
  int s = rem % SEG;
  int col = chunk * 512 + threadIdx.x * 2;
  __shared__ int sidx[SEGL];
  if (threadIdx.x < SEGL)
    sidx[threadIdx.x] = idx[b * LL + s * SEGL + threadIdx.x];
  __syncthreads();
  const float2* ss =
      (const float2*)(segsum + (size_t)((b * CH + chunk) * SEG) * 512) +
      threadIdx.x;
  float a0 = 0.f, a1 = 0.f;
  for (int s2 = 0; s2 < s; ++s2) {
    float2 t = ss[(size_t)s2 * 256];
    a0 += t.x;
    a1 += t.y;
  }
  float2 bias = *(const float2*)(b1 + col);
  const __hip_bfloat162* base = (const __hip_bfloat162*)P + (col >> 1);
  bf16* outp = h + ((size_t)b * LL + (size_t)s * SEGL) * 8192 + col;
#pragma unroll 4
  for (int t = 0; t < SEGL; ++t) {
    __hip_bfloat162 v = base[(size_t)sidx[t] * 4096];
    a0 += __bfloat162float(v.x);
    a1 += __bfloat162float(v.y);
    float inv = __fdividef(1.f, (float)(s * SEGL + t + 1));
    float u0 = a0 * inv + bias.x;
    float u1 = a1 * inv + bias.y;
    __hip_bfloat162 o;
    o.x = __float2bfloat16(0.5f * u0 * (1.f + erff(u0 * 0.70710678118654752f)));
    o.y = __float2bfloat16(0.5f * u1 * (1.f + erff(u1 * 0.70710678118654752f)));
    *(__hip_bfloat162*)(outp + (size_t)t * 8192) = o;
  }
}

// ------- 256x256 bf16 GEMM — r13 champion (balanced+carry+counted vmcnt) --
// 512 thr (2x4 waves), BK=64, 128KiB LDS dbuf, chunk-XOR swizzle (0 confl),
// asm ds_read_b128, 2 BAR/tile. Balanced {8,4,8,4} read phases; B0(t+1)
// ds_read during t.ph4 from ~p, carried in regs across the tile boundary.
// A staged one tile ahead (ph1/ph2 -> ~p), B two ahead (ph3/ph4 -> p).
// Waits: top VMW(4) steady / VMW(0) last tile; mid VMW(6) publishes
// B(t+1,h0) for the carry-read. (r12 tail-race fixed in r13.)
// EPI==1: out = f32 C + bias     EPI==2: out = bf16 C (raw, no bias)

#define BAR() asm volatile("s_barrier" ::: "memory")
#define LGKM0() asm volatile("s_waitcnt lgkmcnt(0)" ::: "memory")
#define VMW(n_) asm volatile("s_waitcnt vmcnt(" #n_ ")" ::: "memory")
#define SB0() __builtin_amdgcn_sched_barrier(0)
#define P1() __builtin_amdgcn_s_setprio(1)
#define P0() __builtin_amdgcn_s_setprio(0)

#define STG_A(t_, h_, b_)                                           \
  {                                                                 \
    const bf16* s_ = Asrc + (size_t)(h_)*128 * K + (size_t)(t_)*64; \
    bf16* d_ = sm + (b_)*32768 + (h_)*8192 + wave * 512;            \
    gload16(s_, d_);                                                \
    gload16(s_ + rowK64, d_ + 4096);                                \
  }
#define STG_B(t_, h_, b_)                                           \
  {                                                                 \
    const bf16* s_ = Bsrc + (size_t)(h_)*128 * K + (size_t)(t_)*64; \
    bf16* d_ = sm + (b_)*32768 + 16384 + (h_)*8192 + wave * 512;    \
    gload16(s_, d_);                                                \
    gload16(s_ + rowK64, d_ + 4096);                                \
  }

#define RD1(dst_, base_, off_)                       \
  asm volatile("ds_read_b128 %0, %1 offset:%2"       \
               : "=v"(dst_)                          \
               : "v"(base_), "i"(off_)               \
               : "memory")

#define RD_A(b0_, b1_, mh_)                    \
  RD1(af[0][0], b0_, (mh_)*16384 + 0);         \
  RD1(af[0][1], b1_, (mh_)*16384 + 0);         \
  RD1(af[1][0], b0_, (mh_)*16384 + 2048);      \
  RD1(af[1][1], b1_, (mh_)*16384 + 2048);      \
  RD1(af[2][0], b0_, (mh_)*16384 + 4096);      \
  RD1(af[2][1], b1_, (mh_)*16384 + 4096);      \
  RD1(af[3][0], b0_, (mh_)*16384 + 6144);      \
  RD1(af[3][1], b1_, (mh_)*16384 + 6144);

#define RD_B(dst_, b0_, b1_, nh_)              \
  RD1(dst_[0][0], b0_, (nh_)*16384 + 0);       \
  RD1(dst_[0][1], b1_, (nh_)*16384 + 0);       \
  RD1(dst_[1][0], b0_, (nh_)*16384 + 2048);    \
  RD1(dst_[1][1], b1_, (nh_)*16384 + 2048);

#define MQ(mh_, nh_, B_)                                                     \
  _Pragma("unroll") for (int i_ = 0; i_ < 4; ++i_)                           \
      _Pragma("unroll") for (int j_ = 0; j_ < 2; ++j_) {                     \
    f32x4& c_ = acc[(mh_)*4 + i_][(nh_)*2 + j_];                             \
    c_ = __builtin_amdgcn_mfma_f32_16x16x32_bf16(as_bf(af[i_][0]),           \
                                                 as_bf(B_[j_][0]), c_, 0, 0, \
                                                 0);                         \
    c_ = __builtin_amdgcn_mfma_f32_16x16x32_bf16(as_bf(af[i_][1]),           \
                                                 as_bf(B_[j_][1]), c_, 0, 0, \
                                                 0);                         \
  }

#define TILE_BODY(T_, p_, aK0_, aK1_, bK0_, bK1_, bn0_, bn1_, Bc_, Bn_) \
  {                                                                     \
    if ((T_) + 1 < NT) { VMW(4); } else { VMW(0); }                     \
    BAR();                                                              \
    RD_A(aK0_, aK1_, 0);                                                \
    if ((T_) + 1 < NT) STG_A((T_) + 1, 0, (p_) ^ 1);                    \
    LGKM0();                                                            \
    SB0();                                                              \
    P1(); MQ(0, 0, Bc_); P0();                                          \
    RD_B(Bn_, bK0_, bK1_, 1);                                           \
    if ((T_) + 1 < NT) STG_A((T_) + 1, 1, (p_) ^ 1);                    \
    LGKM0();                                                            \
    SB0();                                                              \
    P1(); MQ(0, 1, Bn_); P0();                                          \
    VMW(6);                                                             \
    BAR();                                                              \
    RD_A(aK0_, aK1_, 1);                                                \
    if ((T_) + 2 < NT) STG_B((T_) + 2, 0, (p_));                        \
    LGKM0();                                                            \
    SB0();                                                              \
    P1(); MQ(1, 1, Bn_); P0();                                          \
    if ((T_) + 1 < NT) RD_B(Bn_, bn0_, bn1_, 0);                        \
    if ((T_) + 2 < NT) STG_B((T_) + 2, 1, (p_));                        \
    P1(); MQ(1, 0, Bc_); P0();                                          \
  }

template <int EPI>
__global__ __launch_bounds__(512) void gemm256(const bf16* __restrict__ A,
                                               const bf16* __restrict__ Bt,
                                               const float* __restrict__ bias,
                                               void* __restrict__ outv, int M,
                                               int N, int K) {
  __shared__ __align__(16) bf16 sm[65536];  // 128 KiB: 2 x (A 32KB | B 32KB)
  const int tid = threadIdx.x;
  const int wave = tid >> 6;
  const int lane = tid & 63;
  const int nwg = gridDim.x;
  const int bid = blockIdx.x;
  const int swz = (bid & 7) * (nwg >> 3) + (bid >> 3);  // nwg % 8 == 0
  const int gn = N >> 8;
  const int bm0 = (swz / gn) << 8;
  const int bn0 = (swz % gn) << 8;
  const int wm64 = (wave >> 2) << 6;
  const int wn32 = (wave & 3) << 5;
  const int rsel = lane & 15;
  const int ksel = lane >> 4;
  const int xorv = rsel & 7;

  const int r0 = tid >> 3;
  const int kc0 = (tid & 7) ^ (r0 & 7);
  const bf16* Asrc = A + (size_t)(bm0 + r0) * K + kc0 * 8;
  const bf16* Bsrc = Bt + (size_t)(bn0 + r0) * K + kc0 * 8;
  const size_t rowK64 = (size_t)64 * K;
  const int NT = K >> 6;

  const unsigned smbase =
      (unsigned)(unsigned long long)(__attribute__((address_space(3)))
                                     bf16*)sm;
  const unsigned kT0 = (unsigned)((ksel ^ xorv) << 4);
  const unsigned kT1 = (unsigned)(((ksel + 4) ^ xorv) << 4);
  const unsigned aRow = (unsigned)((wm64 + rsel) * 128);
  const unsigned bRow = (unsigned)((wn32 + rsel) * 128);
  const unsigned a00 = smbase + aRow + kT0;
  const unsigned a10 = smbase + aRow + kT1;
  const unsigned b00 = smbase + 32768u + bRow + kT0;
  const unsigned b10 = smbase + 32768u + bRow + kT1;
  const unsigned a01 = a00 + 65536u, a11 = a10 + 65536u;
  const unsigned b01 = b00 + 65536u, b11 = b10 + 65536u;

  f32x4 acc[8][4];
#pragma unroll
  for (int i = 0; i < 8; ++i)
#pragma unroll
    for (int j = 0; j < 4; ++j) acc[i][j] = (f32x4){0.f, 0.f, 0.f, 0.f};

  f32x4 af[4][2], bX[2][2], bY[2][2];

  STG_A(0, 0, 0);
  STG_A(0, 1, 0);
  STG_B(0, 0, 0);
  STG_B(0, 1, 0);
  STG_B(1, 0, 1);
  STG_B(1, 1, 1);
  VMW(4);
  BAR();
  RD_B(bX, b00, b10, 0);

  for (int t = 0; t < NT; t += 2) {
    TILE_BODY(t, 0, a00, a10, b00, b10, b01, b11, bX, bY);
    TILE_BODY(t + 1, 1, a01, a11, b01, b11, b00, b10, bY, bX);
  }

  // epilogue; C/D layout: col = lane&15, row = (lane>>4)*4 + reg
  const int cl = lane & 15;
  const int rg = lane >> 4;
#pragma unroll
  for (int m = 0; m < 8; ++m) {
    int grow = bm0 + ((m >> 2) << 7) + wm64 + ((m & 3) << 4) + rg * 4;
#pragma unroll
    for (int n = 0; n < 4; ++n) {
      int col = bn0 + ((n >> 1) << 7) + wn32 + ((n & 1) << 4) + cl;
      float bv = (EPI == 1) ? bias[col] : 0.f;
#pragma unroll
      for (int r = 0; r < 4; ++r) {
        size_t o = (size_t)(grow + r) * N + col;
        if (EPI == 1) {
          ((float*)outv)[o] = acc[m][n][r] + bv;
        } else {
          ((bf16*)outv)[o] = __float2bfloat16(acc[m][n][r]);
        }
      }
    }
  }
}

extern "C" void kernel_launch(void* const* d_in, const int* in_sizes, int n_in,
                              void* d_out, int out_size, void* d_ws,
                              size_t ws_size, hipStream_t stream) {
  const int* idx = (const int*)d_in[0];       // [B,L]
  const float* Mlog = (const float*)d_in[1];  // [V,V]
  const float* W1 = (const float*)d_in[2];    // [V,2V]
  const float* b1 = (const float*)d_in[3];    // [2V]
  const float* W2 = (const float*)d_in[4];    // [2V,V]
  const float* b2 = (const float*)d_in[5];    // [V]
  float* out = (float*)d_out;                 // [B,L,V] f32

  // Aliased workspace (liveness hand-checked):
  //  [0,64)MB   W1t (dead after GEMM_P) -> segsum 2MB (dead after psumB)
  //             -> W2t
  //  [64,128)   P = R@W1  (bf16 [4096][8192])
  //  [128,256)  h (bf16 [8192][8192]) — written by psumB
  //  [224,256)  R (bf16 [4096][4096]) — dead after GEMM_P, overwritten by h
  char* ws = (char*)d_ws;
  const size_t MB = 1ull << 20;
  bf16* W1t = (bf16*)ws;
  float* segsum = (float*)ws;
  bf16* W2t = (bf16*)ws;
  bf16* P = (bf16*)(ws + 64 * MB);
  bf16* h = (bf16*)(ws + 128 * MB);
  bf16* R = (bf16*)(ws + 224 * MB);
  (void)ws_size;

  dim3 tb(32, 8);
  // W1^T cast
  transpose_f32_bf16<<<dim3(8192 / 32, 4096 / 32), tb, 0, stream>>>(W1, W1t,
                                                                    4096, 8192);
  // R = sigmoid(Mlog) bf16  (16M elems, 4/thread)
  sigmoid_bf16<<<(VOCAB * VOCAB) / 1024, 256, 0, stream>>>(Mlog, R);
  // P = R @ W1  (4096x8192x4096 — HALF the old GEMM1 FLOPs; linearity:
  // cumsum(x)@W1 = cumsum(x@W1) and x@W1 = (R@W1)[idx])
  gemm256<2><<<(4096 / 256) * (8192 / 256), 512, 0, stream>>>(
      R, W1t, b1, P, 4096, 8192, 4096);
  // segment sums + prefix/mean/bias/gelu -> h
  psumA<<<BB * CH * SEG, 256, 0, stream>>>(idx, P, segsum);
  psumB<<<BB * CH * SEG, 256, 0, stream>>>(idx, P, segsum, b1, h);
  // W2^T cast (reuses [0,64))
  transpose_f32_bf16<<<dim3(4096 / 32, 8192 / 32), tb, 0, stream>>>(W2, W2t,
                                                                    8192, 4096);
  // out = h @ W2 + b2  -> f32
  gemm256<1><<<(8192 / 256) * (4096 / 256), 512, 0, stream>>>(
      h, W2t, b2, out, 8192, 4096, 8192);
}

// Round 17
// 790.339 us; speedup vs baseline: 1.7907x; 1.0419x over previous
//
#include <hip/hip_runtime.h>
#include <hip/hip_bf16.h>

#define VOCAB 4096
#define BB 4
#define LL 2048
#define SEG 16
#define SEGL 128  // LL/SEG
#define CH 16     // column chunks of 512 over N=8192

typedef __hip_bfloat16 bf16;
typedef __bf16 bf16x8 __attribute__((ext_vector_type(8)));
typedef float f32x4 __attribute__((ext_vector_type(4)));

__device__ __forceinline__ void gload16(const void* g, void* l) {
  __builtin_amdgcn_global_load_lds(
      (const __attribute__((address_space(1))) unsigned int*)g,
      (__attribute__((address_space(3))) unsigned int*)l, 16, 0, 0);
}

__device__ __forceinline__ bf16x8 as_bf(f32x4 v) {
  union { f32x4 f; bf16x8 b; } u;
  u.f = v;
  return u.b;
}

// ------- transpose f32 [K][N] -> bf16 [N][K], 64x64 tile, 128B stores -----
// load: 128B/wave-instr; store: ushort2/lane = 128B/wave-instr.
// LDS bank check: store-phase lane tx reads word (2tx)*65+j -> bank
// (2tx+j)%32, 2 lanes/bank (free, m136); load phase (i+tx)%32 2-way free.
__global__ void transpose64(const float* __restrict__ in,
                            bf16* __restrict__ out, int K, int N) {
  __shared__ float tile[64][65];
  int n0 = blockIdx.x * 64, k0 = blockIdx.y * 64;
  int tx = threadIdx.x;  // 0..31
  int ty = threadIdx.y;  // 0..7
#pragma unroll
  for (int i = ty; i < 64; i += 8) {
    tile[i][tx] = in[(size_t)(k0 + i) * N + n0 + tx];
    tile[i][tx + 32] = in[(size_t)(k0 + i) * N + n0 + tx + 32];
  }
  __syncthreads();
#pragma unroll
  for (int j = ty; j < 64; j += 8) {
    bf16 two[2];
    two[0] = __float2bfloat16(tile[2 * tx][j]);
    two[1] = __float2bfloat16(tile[2 * tx + 1][j]);
    *(ushort2*)(out + (size_t)(n0 + j) * K + k0 + 2 * tx) = *(ushort2*)two;
  }
}

// ---------------- R = sigmoid(Mlog), f32 -> bf16, 4 elems/thread ----------
__global__ void sigmoid_bf16(const float* __restrict__ in,
                             bf16* __restrict__ out) {
  size_t i = ((size_t)blockIdx.x * 256 + threadIdx.x) * 4;
  float4 v = *(const float4*)(in + i);
  bf16 tmp[4];
  tmp[0] = __float2bfloat16(1.f / (1.f + __expf(-v.x)));
  tmp[1] = __float2bfloat16(1.f / (1.f + __expf(-v.y)));
  tmp[2] = __float2bfloat16(1.f / (1.f + __expf(-v.z)));
  tmp[3] = __float2bfloat16(1.f / (1.f + __expf(-v.w)));
  *(ushort4*)(out + i) = *(ushort4*)tmp;
}

// -------- pass A: per-segment column sums of P[idx] --------
// grid: B * CH * SEG blocks, 256 thr, 2 cols/thread (coalesced row reads)
__global__ void psumA(const int* __restrict__ idx, const bf16* __restrict__ P,
                      float* __restrict__ segsum) {
  int b = blockIdx.x / (CH * SEG);
  int rem = blockIdx.x % (CH * SEG);
  int chunk = rem / SEG;
  int s = rem % SEG;
  int col = chunk * 512 + threadIdx.x * 2;
  __shared__ int sidx[SEGL];
  if (threadIdx.x < SEGL)
    sidx[threadIdx.x] = idx[b * LL + s * SEGL + threadIdx.x];
  __syncthreads();
  const __hip_bfloat162* base = (const __hip_bfloat162*)P + (col >> 1);
  float a0 = 0.f, a1 = 0.f;
#pragma unroll 8
  for (int t = 0; t < SEGL; ++t) {
    __hip_bfloat162 v = base[(size_t)sidx[t] * 4096];
    a0 += __bfloat162float(v.x);
    a1 += __bfloat162float(v.y);
  }
  *((float2*)(segsum + (size_t)blockIdx.x * 512) + threadIdx.x) =
      make_float2(a0, a1);
}

// -------- in-place exclusive prefix over the SEG axis of segsum --------
// grid: B*CH blocks, 256 thr x float2. Tiny (L2-resident).
__global__ void segpre(float* __restrict__ segsum) {
  float2* base =
      (float2*)segsum + (size_t)blockIdx.x * SEG * 256 + threadIdx.x;
  float2 acc = make_float2(0.f, 0.f);
#pragma unroll
  for (int s = 0; s < SEG; ++s) {
    float2 v = base[(size_t)s * 256];
    base[(size_t)s * 256] = acc;
    acc.x += v.x;
    acc.y += v.y;
  }
}

// -------- pass B: prefix(1 load) + running mean + bias + gelu -> h bf16 ---
__global__ void psumB(const int* __restrict__ idx, const bf16* __restrict__ P,
                      const float* __restrict__ segsum,
                      const float* __restrict__ b1, bf16* __restrict__ h) {
  int b = blockIdx.x / (CH * SEG);
  int rem = blockIdx.x % (CH * SEG);
  int chunk = rem / SEG;
  int s = rem % SEG;
  int col = chunk * 512 + threadIdx.x * 2;
  __shared__ int sidx[SEGL];
  if (threadIdx.x < SEGL)
    sidx[threadIdx.x] = idx[b * LL + s * SEGL + threadIdx.x];
  __syncthreads();
  float2 pre = *((const float2*)(segsum + (size_t)blockIdx.x * 512) +
                 threadIdx.x);
  float a0 = pre.x, a1 = pre.y;
  float2 bias = *(const float2*)(b1 + col);
  const __hip_bfloat162* base = (const __hip_bfloat162*)P + (col >> 1);
  bf16* outp = h + ((size_t)b * LL + (size_t)s * SEGL) * 8192 + col;
#pragma unroll 4
  for (int t = 0; t < SEGL; ++t) {
    __hip_bfloat162 v = base[(size_t)sidx[t] * 4096];
    a0 += __bfloat162float(v.x);
    a1 += __bfloat162float(v.y);
    float inv = __fdividef(1.f, (float)(s * SEGL + t + 1));
    float u0 = a0 * inv + bias.x;
    float u1 = a1 * inv + bias.y;
    __hip_bfloat162 o;
    o.x = __float2bfloat16(0.5f * u0 * (1.f + erff(u0 * 0.70710678118654752f)));
    o.y = __float2bfloat16(0.5f * u1 * (1.f + erff(u1 * 0.70710678118654752f)));
    *(__hip_bfloat162*)(outp + (size_t)t * 8192) = o;
  }
}

// ------- 256x256 bf16 GEMM — r13 champion (balanced+carry+counted vmcnt) --
// 512 thr (2x4 waves), BK=64, 128KiB LDS dbuf, chunk-XOR swizzle (0 confl),
// asm ds_read_b128, 2 BAR/tile. Balanced {8,4,8,4} read phases; B0(t+1)
// ds_read during t.ph4 from ~p, carried in regs across the tile boundary.
// A staged one tile ahead (ph1/ph2 -> ~p), B two ahead (ph3/ph4 -> p).
// Waits: top VMW(4) steady / VMW(0) last tile; mid VMW(6) publishes
// B(t+1,h0) for the carry-read. (r12 tail-race fixed in r13.)
// EPI==1: out = f32 C + bias     EPI==2: out = bf16 C (raw, no bias)

#define BAR() asm volatile("s_barrier" ::: "memory")
#define LGKM0() asm volatile("s_waitcnt lgkmcnt(0)" ::: "memory")
#define VMW(n_) asm volatile("s_waitcnt vmcnt(" #n_ ")" ::: "memory")
#define SB0() __builtin_amdgcn_sched_barrier(0)
#define P1() __builtin_amdgcn_s_setprio(1)
#define P0() __builtin_amdgcn_s_setprio(0)

#define STG_A(t_, h_, b_)                                           \
  {                                                                 \
    const bf16* s_ = Asrc + (size_t)(h_)*128 * K + (size_t)(t_)*64; \
    bf16* d_ = sm + (b_)*32768 + (h_)*8192 + wave * 512;            \
    gload16(s_, d_);                                                \
    gload16(s_ + rowK64, d_ + 4096);                                \
  }
#define STG_B(t_, h_, b_)                                           \
  {                                                                 \
    const bf16* s_ = Bsrc + (size_t)(h_)*128 * K + (size_t)(t_)*64; \
    bf16* d_ = sm + (b_)*32768 + 16384 + (h_)*8192 + wave * 512;    \
    gload16(s_, d_);                                                \
    gload16(s_ + rowK64, d_ + 4096);                                \
  }

#define RD1(dst_, base_, off_)                       \
  asm volatile("ds_read_b128 %0, %1 offset:%2"       \
               : "=v"(dst_)                          \
               : "v"(base_), "i"(off_)               \
               : "memory")

#define RD_A(b0_, b1_, mh_)                    \
  RD1(af[0][0], b0_, (mh_)*16384 + 0);         \
  RD1(af[0][1], b1_, (mh_)*16384 + 0);         \
  RD1(af[1][0], b0_, (mh_)*16384 + 2048);      \
  RD1(af[1][1], b1_, (mh_)*16384 + 2048);      \
  RD1(af[2][0], b0_, (mh_)*16384 + 4096);      \
  RD1(af[2][1], b1_, (mh_)*16384 + 4096);      \
  RD1(af[3][0], b0_, (mh_)*16384 + 6144);      \
  RD1(af[3][1], b1_, (mh_)*16384 + 6144);

#define RD_B(dst_, b0_, b1_, nh_)              \
  RD1(dst_[0][0], b0_, (nh_)*16384 + 0);       \
  RD1(dst_[0][1], b1_, (nh_)*16384 + 0);       \
  RD1(dst_[1][0], b0_, (nh_)*16384 + 2048);    \
  RD1(dst_[1][1], b1_, (nh_)*16384 + 2048);

#define MQ(mh_, nh_, B_)                                                     \
  _Pragma("unroll") for (int i_ = 0; i_ < 4; ++i_)                           \
      _Pragma("unroll") for (int j_ = 0; j_ < 2; ++j_) {                     \
    f32x4& c_ = acc[(mh_)*4 + i_][(nh_)*2 + j_];                             \
    c_ = __builtin_amdgcn_mfma_f32_16x16x32_bf16(as_bf(af[i_][0]),           \
                                                 as_bf(B_[j_][0]), c_, 0, 0, \
                                                 0);                         \
    c_ = __builtin_amdgcn_mfma_f32_16x16x32_bf16(as_bf(af[i_][1]),           \
                                                 as_bf(B_[j_][1]), c_, 0, 0, \
                                                 0);                         \
  }

#define TILE_BODY(T_, p_, aK0_, aK1_, bK0_, bK1_, bn0_, bn1_, Bc_, Bn_) \
  {                                                                     \
    if ((T_) + 1 < NT) { VMW(4); } else { VMW(0); }                     \
    BAR();                                                              \
    RD_A(aK0_, aK1_, 0);                                                \
    if ((T_) + 1 < NT) STG_A((T_) + 1, 0, (p_) ^ 1);                    \
    LGKM0();                                                            \
    SB0();                                                              \
    P1(); MQ(0, 0, Bc_); P0();                                          \
    RD_B(Bn_, bK0_, bK1_, 1);                                           \
    if ((T_) + 1 < NT) STG_A((T_) + 1, 1, (p_) ^ 1);                    \
    LGKM0();                                                            \
    SB0();                                                              \
    P1(); MQ(0, 1, Bn_); P0();                                          \
    VMW(6);                                                             \
    BAR();                                                              \
    RD_A(aK0_, aK1_, 1);                                                \
    if ((T_) + 2 < NT) STG_B((T_) + 2, 0, (p_));                        \
    LGKM0();                                                            \
    SB0();                                                              \
    P1(); MQ(1, 1, Bn_); P0();                                          \
    if ((T_) + 1 < NT) RD_B(Bn_, bn0_, bn1_, 0);                        \
    if ((T_) + 2 < NT) STG_B((T_) + 2, 1, (p_));                        \
    P1(); MQ(1, 0, Bc_); P0();                                          \
  }

template <int EPI>
__global__ __launch_bounds__(512) void gemm256(const bf16* __restrict__ A,
                                               const bf16* __restrict__ Bt,
                                               const float* __restrict__ bias,
                                               void* __restrict__ outv, int M,
                                               int N, int K) {
  __shared__ __align__(16) bf16 sm[65536];  // 128 KiB: 2 x (A 32KB | B 32KB)
  const int tid = threadIdx.x;
  const int wave = tid >> 6;
  const int lane = tid & 63;
  const int nwg = gridDim.x;
  const int bid = blockIdx.x;
  const int swz = (bid & 7) * (nwg >> 3) + (bid >> 3);  // nwg % 8 == 0
  const int gn = N >> 8;
  const int bm0 = (swz / gn) << 8;
  const int bn0 = (swz % gn) << 8;
  const int wm64 = (wave >> 2) << 6;
  const int wn32 = (wave & 3) << 5;
  const int rsel = lane & 15;
  const int ksel = lane >> 4;
  const int xorv = rsel & 7;

  const int r0 = tid >> 3;
  const int kc0 = (tid & 7) ^ (r0 & 7);
  const bf16* Asrc = A + (size_t)(bm0 + r0) * K + kc0 * 8;
  const bf16* Bsrc = Bt + (size_t)(bn0 + r0) * K + kc0 * 8;
  const size_t rowK64 = (size_t)64 * K;
  const int NT = K >> 6;

  const unsigned smbase =
      (unsigned)(unsigned long long)(__attribute__((address_space(3)))
                                     bf16*)sm;
  const unsigned kT0 = (unsigned)((ksel ^ xorv) << 4);
  const unsigned kT1 = (unsigned)(((ksel + 4) ^ xorv) << 4);
  const unsigned aRow = (unsigned)((wm64 + rsel) * 128);
  const unsigned bRow = (unsigned)((wn32 + rsel) * 128);
  const unsigned a00 = smbase + aRow + kT0;
  const unsigned a10 = smbase + aRow + kT1;
  const unsigned b00 = smbase + 32768u + bRow + kT0;
  const unsigned b10 = smbase + 32768u + bRow + kT1;
  const unsigned a01 = a00 + 65536u, a11 = a10 + 65536u;
  const unsigned b01 = b00 + 65536u, b11 = b10 + 65536u;

  f32x4 acc[8][4];
#pragma unroll
  for (int i = 0; i < 8; ++i)
#pragma unroll
    for (int j = 0; j < 4; ++j) acc[i][j] = (f32x4){0.f, 0.f, 0.f, 0.f};

  f32x4 af[4][2], bX[2][2], bY[2][2];

  STG_A(0, 0, 0);
  STG_A(0, 1, 0);
  STG_B(0, 0, 0);
  STG_B(0, 1, 0);
  STG_B(1, 0, 1);
  STG_B(1, 1, 1);
  VMW(4);
  BAR();
  RD_B(bX, b00, b10, 0);

  for (int t = 0; t < NT; t += 2) {
    TILE_BODY(t, 0, a00, a10, b00, b10, b01, b11, bX, bY);
    TILE_BODY(t + 1, 1, a01, a11, b01, b11, b00, b10, bY, bX);
  }

  // epilogue; C/D layout: col = lane&15, row = (lane>>4)*4 + reg
  const int cl = lane & 15;
  const int rg = lane >> 4;
#pragma unroll
  for (int m = 0; m < 8; ++m) {
    int grow = bm0 + ((m >> 2) << 7) + wm64 + ((m & 3) << 4) + rg * 4;
#pragma unroll
    for (int n = 0; n < 4; ++n) {
      int col = bn0 + ((n >> 1) << 7) + wn32 + ((n & 1) << 4) + cl;
      float bv = (EPI == 1) ? bias[col] : 0.f;
#pragma unroll
      for (int r = 0; r < 4; ++r) {
        size_t o = (size_t)(grow + r) * N + col;
        if (EPI == 1) {
          ((float*)outv)[o] = acc[m][n][r] + bv;
        } else {
          ((bf16*)outv)[o] = __float2bfloat16(acc[m][n][r]);
        }
      }
    }
  }
}

extern "C" void kernel_launch(void* const* d_in, const int* in_sizes, int n_in,
                              void* d_out, int out_size, void* d_ws,
                              size_t ws_size, hipStream_t stream) {
  const int* idx = (const int*)d_in[0];       // [B,L]
  const float* Mlog = (const float*)d_in[1];  // [V,V]
  const float* W1 = (const float*)d_in[2];    // [V,2V]
  const float* b1 = (const float*)d_in[3];    // [2V]
  const float* W2 = (const float*)d_in[4];    // [2V,V]
  const float* b2 = (const float*)d_in[5];    // [V]
  float* out = (float*)d_out;                 // [B,L,V] f32

  // Aliased workspace (liveness hand-checked):
  //  [0,64)MB   W1t (dead after GEMM_P) -> segsum 2MB (dead after psumB)
  //             -> W2t
  //  [64,128)   P = R@W1  (bf16 [4096][8192])
  //  [128,256)  h (bf16 [8192][8192]) — written by psumB
  //  [224,256)  R (bf16 [4096][4096]) — dead after GEMM_P, overwritten by h
  char* ws = (char*)d_ws;
  const size_t MB = 1ull << 20;
  bf16* W1t = (bf16*)ws;
  float* segsum = (float*)ws;
  bf16* W2t = (bf16*)ws;
  bf16* P = (bf16*)(ws + 64 * MB);
  bf16* h = (bf16*)(ws + 128 * MB);
  bf16* R = (bf16*)(ws + 224 * MB);
  (void)ws_size;

  dim3 tb(32, 8);
  // W1^T cast (64x64 tiles, 128B stores)
  transpose64<<<dim3(8192 / 64, 4096 / 64), tb, 0, stream>>>(W1, W1t, 4096,
                                                             8192);
  // R = sigmoid(Mlog) bf16
  sigmoid_bf16<<<(VOCAB * VOCAB) / 1024, 256, 0, stream>>>(Mlog, R);
  // P = R @ W1  (half the old GEMM1 FLOPs via linearity)
  gemm256<2><<<(4096 / 256) * (8192 / 256), 512, 0, stream>>>(
      R, W1t, b1, P, 4096, 8192, 4096);
  // segment sums -> exclusive prefix -> running mean + bias + gelu -> h
  psumA<<<BB * CH * SEG, 256, 0, stream>>>(idx, P, segsum);
  segpre<<<BB * CH, 256, 0, stream>>>(segsum);
  psumB<<<BB * CH * SEG, 256, 0, stream>>>(idx, P, segsum, b1, h);
  // W2^T cast
  transpose64<<<dim3(4096 / 64, 8192 / 64), tb, 0, stream>>>(W2, W2t, 8192,
                                                             4096);
  // out = h @ W2 + b2  -> f32
  gemm256<1><<<(8192 / 256) * (4096 / 256), 512, 0, stream>>>(
      h, W2t, b2, out, 8192, 4096, 8192);
}